// Round 9
// baseline (473.936 us; speedup 1.0000x reference)
//
#include <hip/hip_runtime.h>
#include <math.h>

// Problem constants (from reference)
#define NN 50000
#define EE 800000
#define NB ((NN + 255) / 256)   // scan blocks

typedef short v8s __attribute__((ext_vector_type(8)));
typedef float v4f __attribute__((ext_vector_type(4)));

__device__ __forceinline__ ushort f2bf(float f) {
    uint u = __float_as_uint(f);
    uint r = (u + 0x7fffu + ((u >> 16) & 1u)) >> 16;
    return (ushort)r;
}
__device__ __forceinline__ float bf2f(ushort h) {
    return __uint_as_float(((uint)h) << 16);
}
// leaky_relu(x,0.2) = 0.6x + 0.4|x|
__device__ __forceinline__ float lrelu(float x) {
    return fmaf(0.4f, fabsf(x), 0.6f * x);
}

// DPP partial reductions (no LDS pipe).
template <int CTRL>
__device__ __forceinline__ float dppadd(float x) {
    int y = __builtin_amdgcn_update_dpp(0, __float_as_int(x), CTRL, 0xf, 0xf, true);
    return x + __int_as_float(y);
}
__device__ __forceinline__ float sum8(float x) {   // all-lane sum within 8-groups
    x = dppadd<0xB1>(x);    // quad_perm xor1
    x = dppadd<0x4E>(x);    // quad_perm xor2
    x = dppadd<0x141>(x);   // row_half_mirror
    return x;
}
__device__ __forceinline__ float sum16(float x) {  // all-lane sum within 16-rows
    x = sum8(x);
    x = dppadd<0x140>(x);   // row_mirror
    return x;
}
__device__ __forceinline__ float expclamp(float t) {
    return __expf(fminf(fmaxf(t, -60.f), 80.f));
}

// ---------------------------------------------------------------------------
// CSR build: histogram -> 2-kernel parallel scan -> scatter
// ---------------------------------------------------------------------------
__global__ __launch_bounds__(256) void k_hist(const int* __restrict__ dst, int* __restrict__ deg) {
    int e = blockIdx.x * 256 + threadIdx.x;
    if (e < EE) atomicAdd(&deg[dst[e]], 1);
}

__global__ __launch_bounds__(256) void k_scan1(const int* __restrict__ deg, int* __restrict__ bsum) {
    __shared__ int sm[4];
    int t = threadIdx.x;
    int idx = blockIdx.x * 256 + t;
    int x = (idx < NN) ? deg[idx] : 0;
    #pragma unroll
    for (int o = 1; o < 64; o <<= 1) x += __shfl_xor(x, o);
    if ((t & 63) == 0) sm[t >> 6] = x;
    __syncthreads();
    if (t == 0) bsum[blockIdx.x] = sm[0] + sm[1] + sm[2] + sm[3];
}

// scan3 with fused block-offset: each block locally scans the NB-entry bsum
// (NB=196 <= 256) to get its own exclusive offset, then scans its 256 degs.
__global__ __launch_bounds__(256) void k_scan3(const int* __restrict__ deg,
                                               const int* __restrict__ bsum,
                                               int* __restrict__ rowptr,
                                               int* __restrict__ cursor) {
    __shared__ int sb[256];
    __shared__ int sm[256];
    int t = threadIdx.x;
    sb[t] = (t < NB) ? bsum[t] : 0;
    __syncthreads();
    for (int o = 1; o < 256; o <<= 1) {
        int a = (t >= o) ? sb[t - o] : 0;
        __syncthreads();
        sb[t] += a;
        __syncthreads();
    }
    const int boff = (blockIdx.x > 0) ? sb[blockIdx.x - 1] : 0;

    int idx = blockIdx.x * 256 + t;
    int v = (idx < NN) ? deg[idx] : 0;
    sm[t] = v;
    __syncthreads();
    for (int o = 1; o < 256; o <<= 1) {
        int a = (t >= o) ? sm[t - o] : 0;
        __syncthreads();
        sm[t] += a;
        __syncthreads();
    }
    int incl = sm[t] + boff;
    if (idx < NN) { rowptr[idx + 1] = incl; cursor[idx] = incl - v; }
    if (idx == 0) rowptr[0] = 0;
}

__global__ __launch_bounds__(256) void k_scatter(const int* __restrict__ src,
                                                 const int* __restrict__ dst,
                                                 int* __restrict__ cursor,
                                                 int* __restrict__ csrc) {
    int e = blockIdx.x * 256 + threadIdx.x;
    if (e < EE) {
        int d = dst[e];
        int pos = atomicAdd(&cursor[d], 1);
        csrc[pos] = src[e];
    }
}

// ---------------------------------------------------------------------------
// Weight conversion: W [128 x FOUT] fp32 -> bf16 hi/lo in MFMA-fragment order:
// element (col = t*16+m, k = c*32+quad*8+j) at (((t*4+c)*4+quad)*16+m)*8+j.
// ---------------------------------------------------------------------------
struct WPack {
    const float* W[8];
    ushort* Th[8];
    ushort* Tl[8];
    int fout[8];
};

__global__ __launch_bounds__(256) void k_conv_w(WPack p) {
    int wi = blockIdx.y;
    int fout = p.fout[wi];
    int total = 128 * fout;
    int i = blockIdx.x * 256 + threadIdx.x;
    if (i >= total) return;
    int k = i / fout;
    int n = i - k * fout;
    float f = p.W[wi][i];
    ushort h = f2bf(f);
    float lo = f - bf2f(h);
    int t = n >> 4, m = n & 15, c = k >> 5, quad = (k >> 3) & 3, j = k & 7;
    int flat = ((((t * 4 + c) * 4 + quad) * 16 + m) << 3) + j;
    p.Th[wi][flat] = h;
    p.Tl[wi][flat] = f2bf(lo);
}

// ---------------------------------------------------------------------------
// Split-bf16 MFMA GEMM, weight-split grid: blockIdx.y = which weight matrix.
// Grid (391, NW) -> 1173 blocks for layer 0/1: ~4.6 blocks/CU (vs 1.5 when
// one block looped over all NW weights) -> latency-hiding for the B loads.
// B fragments read from fragment-packed global (64 KB/matrix, L2-resident —
// 391 blocks share the same addresses). No LDS, no barriers.
// CVT=true: A read from fp32 X and split to bf16 hi/lo on the fly (layer 0).
// ---------------------------------------------------------------------------
template <int FOUT, bool CVT>
__global__ __launch_bounds__(256) void k_gemm_mfma(
    const float* __restrict__ Xf,
    const ushort* __restrict__ Xh, const ushort* __restrict__ Xl,
    const ushort* __restrict__ T0h, const ushort* __restrict__ T0l, const float* __restrict__ B0,
    const ushort* __restrict__ T1h, const ushort* __restrict__ T1l, const float* __restrict__ B1,
    const ushort* __restrict__ T2h, const ushort* __restrict__ T2l,
    float* __restrict__ O0, float* __restrict__ O1, float* __restrict__ O2)
{
    const int lane = threadIdx.x & 63;
    const int wid  = threadIdx.x >> 6;
    const int m    = lane & 15;
    const int quad = lane >> 4;
    const int row0 = blockIdx.x * 128 + wid * 32;
    const int w    = blockIdx.y;

    const ushort* Th[3] = {T0h, T1h, T2h};
    const ushort* Tl[3] = {T0l, T1l, T2l};
    const float*  Bp[3] = {B0, B1, nullptr};
    float*        Op[3] = {O0, O1, O2};
    const ushort* th = Th[w];
    const ushort* tl = Tl[w];
    const float* bias = Bp[w];
    float* O = Op[w];

    v8s ah[2][4], al[2][4];
    #pragma unroll
    for (int s = 0; s < 2; ++s) {
        int arow = row0 + s * 16 + m;
        if (arow > NN - 1) arow = NN - 1;
        #pragma unroll
        for (int c = 0; c < 4; ++c) {
            size_t off = (size_t)arow * 128 + c * 32 + quad * 8;
            if constexpr (CVT) {
                float4 f0 = *(const float4*)(Xf + off);
                float4 f1 = *(const float4*)(Xf + off + 4);
                const float fe[8] = {f0.x, f0.y, f0.z, f0.w, f1.x, f1.y, f1.z, f1.w};
                #pragma unroll
                for (int e = 0; e < 8; ++e) {
                    ushort h = f2bf(fe[e]);
                    float lo = fe[e] - bf2f(h);
                    ah[s][c][e] = (short)h;
                    al[s][c][e] = (short)(__float_as_uint(lo) >> 16);  // truncate lo
                }
            } else {
                ah[s][c] = *(const v8s*)(Xh + off);
                al[s][c] = *(const v8s*)(Xl + off);
            }
        }
    }

    #pragma unroll
    for (int t = 0; t < FOUT / 16; ++t) {
        v4f acc[2] = {{0.f,0.f,0.f,0.f},{0.f,0.f,0.f,0.f}};
        #pragma unroll
        for (int c = 0; c < 4; ++c) {
            int boff = t * 2048 + (c * 4 + quad) * 128 + m * 8;
            v8s bh = *(const v8s*)(th + boff);
            v8s bl = *(const v8s*)(tl + boff);
            acc[0] = __builtin_amdgcn_mfma_f32_16x16x32_bf16(al[0][c], bh, acc[0], 0, 0, 0);
            acc[0] = __builtin_amdgcn_mfma_f32_16x16x32_bf16(ah[0][c], bl, acc[0], 0, 0, 0);
            acc[0] = __builtin_amdgcn_mfma_f32_16x16x32_bf16(ah[0][c], bh, acc[0], 0, 0, 0);
            acc[1] = __builtin_amdgcn_mfma_f32_16x16x32_bf16(al[1][c], bh, acc[1], 0, 0, 0);
            acc[1] = __builtin_amdgcn_mfma_f32_16x16x32_bf16(ah[1][c], bl, acc[1], 0, 0, 0);
            acc[1] = __builtin_amdgcn_mfma_f32_16x16x32_bf16(ah[1][c], bh, acc[1], 0, 0, 0);
        }
        const int col = t * 16 + m;
        float badd = bias ? bias[col] : 0.f;
        #pragma unroll
        for (int s = 0; s < 2; ++s) {
            #pragma unroll
            for (int j = 0; j < 4; ++j) {
                int r = row0 + s * 16 + quad * 4 + j;
                if (r < NN) O[(size_t)r * FOUT + col] = acc[s][j] + badd;
            }
        }
    }
}

// ---------------------------------------------------------------------------
// Aggregation layers 0/1: one wave per node, 4-edge main loop + tail.
// Lane l: half = l>>5 selects edge of the pair; j = l&31 owns channels
// 4j..4j+3 (float4 gather). Head = j>>3 -> logit reduce = sum8 (3 DPP).
// Epilogue: +res +bias, ELU, emit bf16 hi/lo.
// ---------------------------------------------------------------------------
__global__ __launch_bounds__(256) void k_agg01(const float4* __restrict__ XL4,
                                               const float4* __restrict__ XR4,
                                               const float4* __restrict__ RES4,
                                               const float* __restrict__ att,
                                               const float* __restrict__ bias,
                                               const int* __restrict__ rowptr,
                                               const int* __restrict__ csrc,
                                               ushort* __restrict__ Hh,
                                               ushort* __restrict__ Hl) {
    const int lane = threadIdx.x & 63;
    const int wid = threadIdx.x >> 6;
    const int n = blockIdx.x * 4 + wid;
    if (n >= NN) return;
    const int beg = rowptr[n];
    const int end = rowptr[n + 1];
    const int half = lane >> 5;
    const uint j = lane & 31;

    const float4 xr = XR4[(uint)n * 32u + j];
    const float4 at = ((const float4*)att)[j];
    float4 s = {0.f, 0.f, 0.f, 0.f};
    float d = 0.f;

    int i = beg;
    for (; i + 4 <= end; i += 4) {
        uint sa = (uint)csrc[i + half];
        uint sb = (uint)csrc[i + 2 + half];
        float4 va = XL4[sa * 32u + j];
        float4 vb = XL4[sb * 32u + j];
        {
            float t0 = lrelu(va.x + xr.x) * at.x;
            t0 = fmaf(lrelu(va.y + xr.y), at.y, t0);
            t0 = fmaf(lrelu(va.z + xr.z), at.z, t0);
            t0 = fmaf(lrelu(va.w + xr.w), at.w, t0);
            float p = expclamp(sum8(t0));
            d += p;
            s.x = fmaf(p, va.x, s.x); s.y = fmaf(p, va.y, s.y);
            s.z = fmaf(p, va.z, s.z); s.w = fmaf(p, va.w, s.w);
        }
        {
            float t0 = lrelu(vb.x + xr.x) * at.x;
            t0 = fmaf(lrelu(vb.y + xr.y), at.y, t0);
            t0 = fmaf(lrelu(vb.z + xr.z), at.z, t0);
            t0 = fmaf(lrelu(vb.w + xr.w), at.w, t0);
            float p = expclamp(sum8(t0));
            d += p;
            s.x = fmaf(p, vb.x, s.x); s.y = fmaf(p, vb.y, s.y);
            s.z = fmaf(p, vb.z, s.z); s.w = fmaf(p, vb.w, s.w);
        }
    }
    for (; i < end; i += 2) {
        int ia = i + half;
        if (ia > end - 1) ia = end - 1;
        uint sa = (uint)csrc[ia];
        float4 va = XL4[sa * 32u + j];
        float t0 = lrelu(va.x + xr.x) * at.x;
        t0 = fmaf(lrelu(va.y + xr.y), at.y, t0);
        t0 = fmaf(lrelu(va.z + xr.z), at.z, t0);
        t0 = fmaf(lrelu(va.w + xr.w), at.w, t0);
        float p = expclamp(sum8(t0));
        if (half && (i + 1 >= end)) p = 0.f;
        d += p;
        s.x = fmaf(p, va.x, s.x); s.y = fmaf(p, va.y, s.y);
        s.z = fmaf(p, va.z, s.z); s.w = fmaf(p, va.w, s.w);
    }

    d   += __shfl_xor(d, 32);
    s.x += __shfl_xor(s.x, 32);
    s.y += __shfl_xor(s.y, 32);
    s.z += __shfl_xor(s.z, 32);
    s.w += __shfl_xor(s.w, 32);

    if (half == 0) {
        float inv = (d > 0.f) ? 1.f / d : 0.f;
        float4 rv = RES4[(uint)n * 32u + j];
        float4 bv = ((const float4*)bias)[j];
        float o0 = fmaf(s.x, inv, rv.x + bv.x);
        float o1 = fmaf(s.y, inv, rv.y + bv.y);
        float o2 = fmaf(s.z, inv, rv.z + bv.z);
        float o3 = fmaf(s.w, inv, rv.w + bv.w);
        o0 = o0 > 0.f ? o0 : __expf(o0) - 1.f;   // ELU
        o1 = o1 > 0.f ? o1 : __expf(o1) - 1.f;
        o2 = o2 > 0.f ? o2 : __expf(o2) - 1.f;
        o3 = o3 > 0.f ? o3 : __expf(o3) - 1.f;
        ushort4 h, l;
        h.x = f2bf(o0); l.x = f2bf(o0 - bf2f(h.x));
        h.y = f2bf(o1); l.y = f2bf(o1 - bf2f(h.y));
        h.z = f2bf(o2); l.z = f2bf(o2 - bf2f(h.z));
        h.w = f2bf(o3); l.w = f2bf(o3 - bf2f(h.w));
        *(ushort4*)(Hh + (uint)n * 128u + 4u * j) = h;
        *(ushort4*)(Hl + (uint)n * 128u + 4u * j) = l;
    }
}

// ---------------------------------------------------------------------------
// Aggregation layer 2: F=64, H=1. 8 edges per iteration (2 masked quad-passes).
// Quarter q = l>>4 selects edge; jj = l&15 owns channels 4jj..4jj+3.
// ---------------------------------------------------------------------------
__global__ __launch_bounds__(256) void k_agg2(const float4* __restrict__ XL4,
                                              const float4* __restrict__ XR4,
                                              const float* __restrict__ att,
                                              const float* __restrict__ bias,
                                              const int* __restrict__ rowptr,
                                              const int* __restrict__ csrc,
                                              float* __restrict__ OUT) {
    const int lane = threadIdx.x & 63;
    const int wid = threadIdx.x >> 6;
    const int n = blockIdx.x * 4 + wid;
    if (n >= NN) return;
    const int beg = rowptr[n];
    const int end = rowptr[n + 1];
    const int q = lane >> 4;
    const uint jj = lane & 15;

    const float4 xr = XR4[(uint)n * 16u + jj];
    const float4 at = ((const float4*)att)[jj];
    float4 s = {0.f, 0.f, 0.f, 0.f};
    float d = 0.f;
    const int e1 = end - 1;

    for (int i = beg; i < end; i += 8) {
        int i0 = i + q;
        int i1 = i + 4 + q;
        uint s0 = (uint)csrc[min(i0, e1)];
        uint s1 = (uint)csrc[min(i1, e1)];
        float4 v0 = XL4[s0 * 16u + jj];
        float4 v1 = XL4[s1 * 16u + jj];
        #pragma unroll
        for (int u = 0; u < 2; ++u) {
            float4 v = (u == 0) ? v0 : v1;
            int ii = (u == 0) ? i0 : i1;
            float t0 = lrelu(v.x + xr.x) * at.x;
            t0 = fmaf(lrelu(v.y + xr.y), at.y, t0);
            t0 = fmaf(lrelu(v.z + xr.z), at.z, t0);
            t0 = fmaf(lrelu(v.w + xr.w), at.w, t0);
            float p = expclamp(sum16(t0));
            if (ii >= end) p = 0.f;
            d += p;
            s.x = fmaf(p, v.x, s.x); s.y = fmaf(p, v.y, s.y);
            s.z = fmaf(p, v.z, s.z); s.w = fmaf(p, v.w, s.w);
        }
    }

    d   += __shfl_xor(d, 16);   d   += __shfl_xor(d, 32);
    s.x += __shfl_xor(s.x, 16); s.x += __shfl_xor(s.x, 32);
    s.y += __shfl_xor(s.y, 16); s.y += __shfl_xor(s.y, 32);
    s.z += __shfl_xor(s.z, 16); s.z += __shfl_xor(s.z, 32);
    s.w += __shfl_xor(s.w, 16); s.w += __shfl_xor(s.w, 32);

    if (lane < 16) {
        float inv = (d > 0.f) ? 1.f / d : 0.f;
        float4 bv = ((const float4*)bias)[jj];
        float4 o;
        o.x = fmaf(s.x, inv, bv.x);
        o.y = fmaf(s.y, inv, bv.y);
        o.z = fmaf(s.z, inv, bv.z);
        o.w = fmaf(s.w, inv, bv.w);
        *(float4*)(OUT + (uint)n * 64u + 4u * jj) = o;
    }
}

// ---------------------------------------------------------------------------
extern "C" void kernel_launch(void* const* d_in, const int* in_sizes, int n_in,
                              void* d_out, int out_size, void* d_ws, size_t ws_size,
                              hipStream_t stream) {
    const float* x    = (const float*)d_in[0];
    const int*   ei   = (const int*)d_in[1];
    const int*   esrc = ei;
    const int*   edst = ei + EE;

    const float* Wl0 = (const float*)d_in[2];
    const float* bl0 = (const float*)d_in[3];
    const float* Wr0 = (const float*)d_in[4];
    const float* br0 = (const float*)d_in[5];
    const float* at0 = (const float*)d_in[6];
    const float* b0  = (const float*)d_in[7];
    const float* rs0 = (const float*)d_in[8];
    const float* Wl1 = (const float*)d_in[9];
    const float* bl1 = (const float*)d_in[10];
    const float* Wr1 = (const float*)d_in[11];
    const float* br1 = (const float*)d_in[12];
    const float* at1 = (const float*)d_in[13];
    const float* b1  = (const float*)d_in[14];
    const float* rs1 = (const float*)d_in[15];
    const float* Wl2 = (const float*)d_in[16];
    const float* bl2 = (const float*)d_in[17];
    const float* Wr2 = (const float*)d_in[18];
    const float* br2 = (const float*)d_in[19];
    const float* at2 = (const float*)d_in[20];
    const float* b2  = (const float*)d_in[21];

    float* out = (float*)d_out;

    // --- workspace layout ---
    float* XL  = (float*)d_ws;                 // [NN*128] fp32 row-major
    float* XR  = XL + (size_t)NN * 128;
    float* RES = XR + (size_t)NN * 128;
    ushort* Xh = (ushort*)(RES + (size_t)NN * 128);   // [NN*128] bf16-hi (H)
    ushort* Xl_ = Xh + (size_t)NN * 128;              // [NN*128] bf16-lo (H)
    ushort* Wth = Xl_ + (size_t)NN * 128;
    const int wsz[8] = {16384, 16384, 16384, 16384, 16384, 16384, 8192, 8192};
    ushort* th[8]; ushort* tl[8];
    {
        ushort* p = Wth;
        for (int i = 0; i < 8; ++i) { th[i] = p; p += wsz[i]; }
        for (int i = 0; i < 8; ++i) { tl[i] = p; p += wsz[i]; }
    }
    int* deg    = (int*)(Wth + 2 * (6 * 16384 + 2 * 8192));
    int* rowptr = deg + NN;                    // NN+1
    int* cursor = rowptr + (NN + 1);
    int* csrc   = cursor + NN;                 // EE
    int* bsum   = csrc + EE;                   // NB

    // --- CSR build (graph identical across layers) ---
    hipMemsetAsync(deg, 0, NN * sizeof(int), stream);
    k_hist<<<(EE + 255) / 256, 256, 0, stream>>>(edst, deg);
    k_scan1<<<NB, 256, 0, stream>>>(deg, bsum);
    k_scan3<<<NB, 256, 0, stream>>>(deg, bsum, rowptr, cursor);
    k_scatter<<<(EE + 255) / 256, 256, 0, stream>>>(esrc, edst, cursor, csrc);

    // --- weight conversion ---
    WPack wp;
    const float* Ws[8] = {Wl0, Wr0, rs0, Wl1, Wr1, rs1, Wl2, Wr2};
    const int fouts[8] = {128, 128, 128, 128, 128, 128, 64, 64};
    for (int i = 0; i < 8; ++i) { wp.W[i] = Ws[i]; wp.Th[i] = th[i]; wp.Tl[i] = tl[i]; wp.fout[i] = fouts[i]; }
    k_conv_w<<<dim3(64, 8), 256, 0, stream>>>(wp);

    const int gemm_gx = (NN + 127) / 128;
    const int agg_grid = (NN + 3) / 4;

    // --- Layer 0 (A from fp32 x, split on the fly; grid.y = weight matrix) ---
    k_gemm_mfma<128, true><<<dim3(gemm_gx, 3), 256, 0, stream>>>(x, nullptr, nullptr,
        th[0], tl[0], bl0, th[1], tl[1], br0, th[2], tl[2], XL, XR, RES);
    k_agg01<<<agg_grid, 256, 0, stream>>>((const float4*)XL, (const float4*)XR, (const float4*)RES,
        at0, b0, rowptr, csrc, Xh, Xl_);

    // --- Layer 1 ---
    k_gemm_mfma<128, false><<<dim3(gemm_gx, 3), 256, 0, stream>>>(nullptr, Xh, Xl_,
        th[3], tl[3], bl1, th[4], tl[4], br1, th[5], tl[5], XL, XR, RES);
    k_agg01<<<agg_grid, 256, 0, stream>>>((const float4*)XL, (const float4*)XR, (const float4*)RES,
        at1, b1, rowptr, csrc, Xh, Xl_);

    // --- Layer 2 (heads=1, C=64, no residual, no ELU) ---
    k_gemm_mfma<64, false><<<dim3(gemm_gx, 2), 256, 0, stream>>>(nullptr, Xh, Xl_,
        th[6], tl[6], bl2, th[7], tl[7], br2, nullptr, nullptr, XL, XR, nullptr);
    k_agg2<<<agg_grid, 256, 0, stream>>>((const float4*)XL, (const float4*)XR, at2, b2, rowptr, csrc, out);
}

// Round 10
// 461.236 us; speedup vs baseline: 1.0275x; 1.0275x over previous
//
#include <hip/hip_runtime.h>
#include <math.h>

// Problem constants (from reference)
#define NN 50000
#define EE 800000
#define NB ((NN + 255) / 256)   // scan blocks

typedef short v8s __attribute__((ext_vector_type(8)));
typedef float v4f __attribute__((ext_vector_type(4)));

__device__ __forceinline__ ushort f2bf(float f) {
    uint u = __float_as_uint(f);
    uint r = (u + 0x7fffu + ((u >> 16) & 1u)) >> 16;
    return (ushort)r;
}
__device__ __forceinline__ float bf2f(ushort h) {
    return __uint_as_float(((uint)h) << 16);
}
// leaky_relu(x,0.2) = 0.6x + 0.4|x|
__device__ __forceinline__ float lrelu(float x) {
    return fmaf(0.4f, fabsf(x), 0.6f * x);
}

// DPP partial reductions (no LDS pipe).
template <int CTRL>
__device__ __forceinline__ float dppadd(float x) {
    int y = __builtin_amdgcn_update_dpp(0, __float_as_int(x), CTRL, 0xf, 0xf, true);
    return x + __int_as_float(y);
}
__device__ __forceinline__ float sum8(float x) {   // all-lane sum within 8-groups
    x = dppadd<0xB1>(x);    // quad_perm xor1
    x = dppadd<0x4E>(x);    // quad_perm xor2
    x = dppadd<0x141>(x);   // row_half_mirror
    return x;
}
__device__ __forceinline__ float sum16(float x) {  // all-lane sum within 16-rows
    x = sum8(x);
    x = dppadd<0x140>(x);   // row_mirror
    return x;
}
__device__ __forceinline__ float expclamp(float t) {
    return __expf(fminf(fmaxf(t, -60.f), 80.f));
}

// ---------------------------------------------------------------------------
// CSR build: histogram -> 2-kernel parallel scan -> scatter
// ---------------------------------------------------------------------------
__global__ __launch_bounds__(256) void k_hist(const int* __restrict__ dst, int* __restrict__ deg) {
    int e = blockIdx.x * 256 + threadIdx.x;
    if (e < EE) atomicAdd(&deg[dst[e]], 1);
}

__global__ __launch_bounds__(256) void k_scan1(const int* __restrict__ deg, int* __restrict__ bsum) {
    __shared__ int sm[4];
    int t = threadIdx.x;
    int idx = blockIdx.x * 256 + t;
    int x = (idx < NN) ? deg[idx] : 0;
    #pragma unroll
    for (int o = 1; o < 64; o <<= 1) x += __shfl_xor(x, o);
    if ((t & 63) == 0) sm[t >> 6] = x;
    __syncthreads();
    if (t == 0) bsum[blockIdx.x] = sm[0] + sm[1] + sm[2] + sm[3];
}

// scan3 with fused block-offset: each block locally scans the NB-entry bsum
// (NB=196 <= 256) to get its own exclusive offset, then scans its 256 degs.
__global__ __launch_bounds__(256) void k_scan3(const int* __restrict__ deg,
                                               const int* __restrict__ bsum,
                                               int* __restrict__ rowptr,
                                               int* __restrict__ cursor) {
    __shared__ int sb[256];
    __shared__ int sm[256];
    int t = threadIdx.x;
    sb[t] = (t < NB) ? bsum[t] : 0;
    __syncthreads();
    for (int o = 1; o < 256; o <<= 1) {
        int a = (t >= o) ? sb[t - o] : 0;
        __syncthreads();
        sb[t] += a;
        __syncthreads();
    }
    const int boff = (blockIdx.x > 0) ? sb[blockIdx.x - 1] : 0;

    int idx = blockIdx.x * 256 + t;
    int v = (idx < NN) ? deg[idx] : 0;
    sm[t] = v;
    __syncthreads();
    for (int o = 1; o < 256; o <<= 1) {
        int a = (t >= o) ? sm[t - o] : 0;
        __syncthreads();
        sm[t] += a;
        __syncthreads();
    }
    int incl = sm[t] + boff;
    if (idx < NN) { rowptr[idx + 1] = incl; cursor[idx] = incl - v; }
    if (idx == 0) rowptr[0] = 0;
}

__global__ __launch_bounds__(256) void k_scatter(const int* __restrict__ src,
                                                 const int* __restrict__ dst,
                                                 int* __restrict__ cursor,
                                                 int* __restrict__ csrc) {
    int e = blockIdx.x * 256 + threadIdx.x;
    if (e < EE) {
        int d = dst[e];
        int pos = atomicAdd(&cursor[d], 1);
        csrc[pos] = src[e];
    }
}

// ---------------------------------------------------------------------------
// Weight conversion: W [128 x FOUT] fp32 -> bf16 hi/lo in MFMA-fragment order:
// element (col = t*16+m, k = c*32+quad*8+j) at (((t*4+c)*4+quad)*16+m)*8+j.
// ---------------------------------------------------------------------------
struct WPack {
    const float* W[8];
    ushort* Th[8];
    ushort* Tl[8];
    int fout[8];
};

__global__ __launch_bounds__(256) void k_conv_w(WPack p) {
    int wi = blockIdx.y;
    int fout = p.fout[wi];
    int total = 128 * fout;
    int i = blockIdx.x * 256 + threadIdx.x;
    if (i >= total) return;
    int k = i / fout;
    int n = i - k * fout;
    float f = p.W[wi][i];
    ushort h = f2bf(f);
    float lo = f - bf2f(h);
    int t = n >> 4, m = n & 15, c = k >> 5, quad = (k >> 3) & 3, j = k & 7;
    int flat = ((((t * 4 + c) * 4 + quad) * 16 + m) << 3) + j;
    p.Th[wi][flat] = h;
    p.Tl[wi][flat] = f2bf(lo);
}

// ---------------------------------------------------------------------------
// Split-bf16 MFMA GEMM, max-parallelism variant: 64 rows per block (one
// 16-row strip per wave), blockIdx.y = weight matrix. Grid (782, NW) = 2346
// blocks (~9 blocks/CU) — enough concurrent waves to hide the L2-resident
// B-fragment load latency (round-8 PMC: MfmaUtil 7%, Occ 16% at 1.5 blk/CU).
// No LDS, no barriers. CVT=true: A read from fp32 X, split hi/lo on the fly.
// ---------------------------------------------------------------------------
template <int FOUT, bool CVT>
__global__ __launch_bounds__(256) void k_gemm_mfma(
    const float* __restrict__ Xf,
    const ushort* __restrict__ Xh, const ushort* __restrict__ Xl,
    const ushort* __restrict__ T0h, const ushort* __restrict__ T0l, const float* __restrict__ B0,
    const ushort* __restrict__ T1h, const ushort* __restrict__ T1l, const float* __restrict__ B1,
    const ushort* __restrict__ T2h, const ushort* __restrict__ T2l,
    float* __restrict__ O0, float* __restrict__ O1, float* __restrict__ O2)
{
    const int lane = threadIdx.x & 63;
    const int wid  = threadIdx.x >> 6;
    const int m    = lane & 15;
    const int quad = lane >> 4;
    const int row0 = blockIdx.x * 64 + wid * 16;
    const int w    = blockIdx.y;

    const ushort* Th[3] = {T0h, T1h, T2h};
    const ushort* Tl[3] = {T0l, T1l, T2l};
    const float*  Bp[3] = {B0, B1, nullptr};
    float*        Op[3] = {O0, O1, O2};
    const ushort* th = Th[w];
    const ushort* tl = Tl[w];
    const float* bias = Bp[w];
    float* O = Op[w];

    v8s ah[4], al[4];
    {
        int arow = row0 + m;
        if (arow > NN - 1) arow = NN - 1;
        #pragma unroll
        for (int c = 0; c < 4; ++c) {
            size_t off = (size_t)arow * 128 + c * 32 + quad * 8;
            if constexpr (CVT) {
                float4 f0 = *(const float4*)(Xf + off);
                float4 f1 = *(const float4*)(Xf + off + 4);
                const float fe[8] = {f0.x, f0.y, f0.z, f0.w, f1.x, f1.y, f1.z, f1.w};
                #pragma unroll
                for (int e = 0; e < 8; ++e) {
                    ushort h = f2bf(fe[e]);
                    float lo = fe[e] - bf2f(h);
                    ah[c][e] = (short)h;
                    al[c][e] = (short)(__float_as_uint(lo) >> 16);  // truncate lo
                }
            } else {
                ah[c] = *(const v8s*)(Xh + off);
                al[c] = *(const v8s*)(Xl + off);
            }
        }
    }

    #pragma unroll
    for (int t = 0; t < FOUT / 16; ++t) {
        v4f acc = {0.f, 0.f, 0.f, 0.f};
        #pragma unroll
        for (int c = 0; c < 4; ++c) {
            int boff = t * 2048 + (c * 4 + quad) * 128 + m * 8;
            v8s bh = *(const v8s*)(th + boff);
            v8s bl = *(const v8s*)(tl + boff);
            acc = __builtin_amdgcn_mfma_f32_16x16x32_bf16(al[c], bh, acc, 0, 0, 0);
            acc = __builtin_amdgcn_mfma_f32_16x16x32_bf16(ah[c], bl, acc, 0, 0, 0);
            acc = __builtin_amdgcn_mfma_f32_16x16x32_bf16(ah[c], bh, acc, 0, 0, 0);
        }
        const int col = t * 16 + m;
        float badd = bias ? bias[col] : 0.f;
        #pragma unroll
        for (int j = 0; j < 4; ++j) {
            int r = row0 + quad * 4 + j;
            if (r < NN) O[(size_t)r * FOUT + col] = acc[j] + badd;
        }
    }
}

// ---------------------------------------------------------------------------
// Aggregation layers 0/1: one wave per node, 4-edge main loop + tail.
// Lane l: half = l>>5 selects edge of the pair; j = l&31 owns channels
// 4j..4j+3 (float4 gather). Head = j>>3 -> logit reduce = sum8 (3 DPP).
// Epilogue: +res +bias, ELU, emit bf16 hi/lo.
// ---------------------------------------------------------------------------
__global__ __launch_bounds__(256) void k_agg01(const float4* __restrict__ XL4,
                                               const float4* __restrict__ XR4,
                                               const float4* __restrict__ RES4,
                                               const float* __restrict__ att,
                                               const float* __restrict__ bias,
                                               const int* __restrict__ rowptr,
                                               const int* __restrict__ csrc,
                                               ushort* __restrict__ Hh,
                                               ushort* __restrict__ Hl) {
    const int lane = threadIdx.x & 63;
    const int wid = threadIdx.x >> 6;
    const int n = blockIdx.x * 4 + wid;
    if (n >= NN) return;
    const int beg = rowptr[n];
    const int end = rowptr[n + 1];
    const int half = lane >> 5;
    const uint j = lane & 31;

    const float4 xr = XR4[(uint)n * 32u + j];
    const float4 at = ((const float4*)att)[j];
    float4 s = {0.f, 0.f, 0.f, 0.f};
    float d = 0.f;

    int i = beg;
    for (; i + 4 <= end; i += 4) {
        uint sa = (uint)csrc[i + half];
        uint sb = (uint)csrc[i + 2 + half];
        float4 va = XL4[sa * 32u + j];
        float4 vb = XL4[sb * 32u + j];
        {
            float t0 = lrelu(va.x + xr.x) * at.x;
            t0 = fmaf(lrelu(va.y + xr.y), at.y, t0);
            t0 = fmaf(lrelu(va.z + xr.z), at.z, t0);
            t0 = fmaf(lrelu(va.w + xr.w), at.w, t0);
            float p = expclamp(sum8(t0));
            d += p;
            s.x = fmaf(p, va.x, s.x); s.y = fmaf(p, va.y, s.y);
            s.z = fmaf(p, va.z, s.z); s.w = fmaf(p, va.w, s.w);
        }
        {
            float t0 = lrelu(vb.x + xr.x) * at.x;
            t0 = fmaf(lrelu(vb.y + xr.y), at.y, t0);
            t0 = fmaf(lrelu(vb.z + xr.z), at.z, t0);
            t0 = fmaf(lrelu(vb.w + xr.w), at.w, t0);
            float p = expclamp(sum8(t0));
            d += p;
            s.x = fmaf(p, vb.x, s.x); s.y = fmaf(p, vb.y, s.y);
            s.z = fmaf(p, vb.z, s.z); s.w = fmaf(p, vb.w, s.w);
        }
    }
    for (; i < end; i += 2) {
        int ia = i + half;
        if (ia > end - 1) ia = end - 1;
        uint sa = (uint)csrc[ia];
        float4 va = XL4[sa * 32u + j];
        float t0 = lrelu(va.x + xr.x) * at.x;
        t0 = fmaf(lrelu(va.y + xr.y), at.y, t0);
        t0 = fmaf(lrelu(va.z + xr.z), at.z, t0);
        t0 = fmaf(lrelu(va.w + xr.w), at.w, t0);
        float p = expclamp(sum8(t0));
        if (half && (i + 1 >= end)) p = 0.f;
        d += p;
        s.x = fmaf(p, va.x, s.x); s.y = fmaf(p, va.y, s.y);
        s.z = fmaf(p, va.z, s.z); s.w = fmaf(p, va.w, s.w);
    }

    d   += __shfl_xor(d, 32);
    s.x += __shfl_xor(s.x, 32);
    s.y += __shfl_xor(s.y, 32);
    s.z += __shfl_xor(s.z, 32);
    s.w += __shfl_xor(s.w, 32);

    if (half == 0) {
        float inv = (d > 0.f) ? 1.f / d : 0.f;
        float4 rv = RES4[(uint)n * 32u + j];
        float4 bv = ((const float4*)bias)[j];
        float o0 = fmaf(s.x, inv, rv.x + bv.x);
        float o1 = fmaf(s.y, inv, rv.y + bv.y);
        float o2 = fmaf(s.z, inv, rv.z + bv.z);
        float o3 = fmaf(s.w, inv, rv.w + bv.w);
        o0 = o0 > 0.f ? o0 : __expf(o0) - 1.f;   // ELU
        o1 = o1 > 0.f ? o1 : __expf(o1) - 1.f;
        o2 = o2 > 0.f ? o2 : __expf(o2) - 1.f;
        o3 = o3 > 0.f ? o3 : __expf(o3) - 1.f;
        ushort4 h, l;
        h.x = f2bf(o0); l.x = f2bf(o0 - bf2f(h.x));
        h.y = f2bf(o1); l.y = f2bf(o1 - bf2f(h.y));
        h.z = f2bf(o2); l.z = f2bf(o2 - bf2f(h.z));
        h.w = f2bf(o3); l.w = f2bf(o3 - bf2f(h.w));
        *(ushort4*)(Hh + (uint)n * 128u + 4u * j) = h;
        *(ushort4*)(Hl + (uint)n * 128u + 4u * j) = l;
    }
}

// ---------------------------------------------------------------------------
// Aggregation layer 2: F=64, H=1. 8 edges per iteration (2 masked quad-passes).
// Quarter q = l>>4 selects edge; jj = l&15 owns channels 4jj..4jj+3.
// ---------------------------------------------------------------------------
__global__ __launch_bounds__(256) void k_agg2(const float4* __restrict__ XL4,
                                              const float4* __restrict__ XR4,
                                              const float* __restrict__ att,
                                              const float* __restrict__ bias,
                                              const int* __restrict__ rowptr,
                                              const int* __restrict__ csrc,
                                              float* __restrict__ OUT) {
    const int lane = threadIdx.x & 63;
    const int wid = threadIdx.x >> 6;
    const int n = blockIdx.x * 4 + wid;
    if (n >= NN) return;
    const int beg = rowptr[n];
    const int end = rowptr[n + 1];
    const int q = lane >> 4;
    const uint jj = lane & 15;

    const float4 xr = XR4[(uint)n * 16u + jj];
    const float4 at = ((const float4*)att)[jj];
    float4 s = {0.f, 0.f, 0.f, 0.f};
    float d = 0.f;
    const int e1 = end - 1;

    for (int i = beg; i < end; i += 8) {
        int i0 = i + q;
        int i1 = i + 4 + q;
        uint s0 = (uint)csrc[min(i0, e1)];
        uint s1 = (uint)csrc[min(i1, e1)];
        float4 v0 = XL4[s0 * 16u + jj];
        float4 v1 = XL4[s1 * 16u + jj];
        #pragma unroll
        for (int u = 0; u < 2; ++u) {
            float4 v = (u == 0) ? v0 : v1;
            int ii = (u == 0) ? i0 : i1;
            float t0 = lrelu(v.x + xr.x) * at.x;
            t0 = fmaf(lrelu(v.y + xr.y), at.y, t0);
            t0 = fmaf(lrelu(v.z + xr.z), at.z, t0);
            t0 = fmaf(lrelu(v.w + xr.w), at.w, t0);
            float p = expclamp(sum16(t0));
            if (ii >= end) p = 0.f;
            d += p;
            s.x = fmaf(p, v.x, s.x); s.y = fmaf(p, v.y, s.y);
            s.z = fmaf(p, v.z, s.z); s.w = fmaf(p, v.w, s.w);
        }
    }

    d   += __shfl_xor(d, 16);   d   += __shfl_xor(d, 32);
    s.x += __shfl_xor(s.x, 16); s.x += __shfl_xor(s.x, 32);
    s.y += __shfl_xor(s.y, 16); s.y += __shfl_xor(s.y, 32);
    s.z += __shfl_xor(s.z, 16); s.z += __shfl_xor(s.z, 32);
    s.w += __shfl_xor(s.w, 16); s.w += __shfl_xor(s.w, 32);

    if (lane < 16) {
        float inv = (d > 0.f) ? 1.f / d : 0.f;
        float4 bv = ((const float4*)bias)[jj];
        float4 o;
        o.x = fmaf(s.x, inv, bv.x);
        o.y = fmaf(s.y, inv, bv.y);
        o.z = fmaf(s.z, inv, bv.z);
        o.w = fmaf(s.w, inv, bv.w);
        *(float4*)(OUT + (uint)n * 64u + 4u * jj) = o;
    }
}

// ---------------------------------------------------------------------------
extern "C" void kernel_launch(void* const* d_in, const int* in_sizes, int n_in,
                              void* d_out, int out_size, void* d_ws, size_t ws_size,
                              hipStream_t stream) {
    const float* x    = (const float*)d_in[0];
    const int*   ei   = (const int*)d_in[1];
    const int*   esrc = ei;
    const int*   edst = ei + EE;

    const float* Wl0 = (const float*)d_in[2];
    const float* bl0 = (const float*)d_in[3];
    const float* Wr0 = (const float*)d_in[4];
    const float* br0 = (const float*)d_in[5];
    const float* at0 = (const float*)d_in[6];
    const float* b0  = (const float*)d_in[7];
    const float* rs0 = (const float*)d_in[8];
    const float* Wl1 = (const float*)d_in[9];
    const float* bl1 = (const float*)d_in[10];
    const float* Wr1 = (const float*)d_in[11];
    const float* br1 = (const float*)d_in[12];
    const float* at1 = (const float*)d_in[13];
    const float* b1  = (const float*)d_in[14];
    const float* rs1 = (const float*)d_in[15];
    const float* Wl2 = (const float*)d_in[16];
    const float* bl2 = (const float*)d_in[17];
    const float* Wr2 = (const float*)d_in[18];
    const float* br2 = (const float*)d_in[19];
    const float* at2 = (const float*)d_in[20];
    const float* b2  = (const float*)d_in[21];

    float* out = (float*)d_out;

    // --- workspace layout ---
    float* XL  = (float*)d_ws;                 // [NN*128] fp32 row-major
    float* XR  = XL + (size_t)NN * 128;
    float* RES = XR + (size_t)NN * 128;
    ushort* Xh = (ushort*)(RES + (size_t)NN * 128);   // [NN*128] bf16-hi (H)
    ushort* Xl_ = Xh + (size_t)NN * 128;              // [NN*128] bf16-lo (H)
    ushort* Wth = Xl_ + (size_t)NN * 128;
    const int wsz[8] = {16384, 16384, 16384, 16384, 16384, 16384, 8192, 8192};
    ushort* th[8]; ushort* tl[8];
    {
        ushort* p = Wth;
        for (int i = 0; i < 8; ++i) { th[i] = p; p += wsz[i]; }
        for (int i = 0; i < 8; ++i) { tl[i] = p; p += wsz[i]; }
    }
    int* deg    = (int*)(Wth + 2 * (6 * 16384 + 2 * 8192));
    int* rowptr = deg + NN;                    // NN+1
    int* cursor = rowptr + (NN + 1);
    int* csrc   = cursor + NN;                 // EE
    int* bsum   = csrc + EE;                   // NB

    // --- CSR build (graph identical across layers) ---
    hipMemsetAsync(deg, 0, NN * sizeof(int), stream);
    k_hist<<<(EE + 255) / 256, 256, 0, stream>>>(edst, deg);
    k_scan1<<<NB, 256, 0, stream>>>(deg, bsum);
    k_scan3<<<NB, 256, 0, stream>>>(deg, bsum, rowptr, cursor);
    k_scatter<<<(EE + 255) / 256, 256, 0, stream>>>(esrc, edst, cursor, csrc);

    // --- weight conversion ---
    WPack wp;
    const float* Ws[8] = {Wl0, Wr0, rs0, Wl1, Wr1, rs1, Wl2, Wr2};
    const int fouts[8] = {128, 128, 128, 128, 128, 128, 64, 64};
    for (int i = 0; i < 8; ++i) { wp.W[i] = Ws[i]; wp.Th[i] = th[i]; wp.Tl[i] = tl[i]; wp.fout[i] = fouts[i]; }
    k_conv_w<<<dim3(64, 8), 256, 0, stream>>>(wp);

    const int gemm_gx = (NN + 63) / 64;        // 782 row-tiles
    const int agg_grid = (NN + 3) / 4;

    // --- Layer 0 (A from fp32 x, split on the fly; grid.y = weight matrix) ---
    k_gemm_mfma<128, true><<<dim3(gemm_gx, 3), 256, 0, stream>>>(x, nullptr, nullptr,
        th[0], tl[0], bl0, th[1], tl[1], br0, th[2], tl[2], XL, XR, RES);
    k_agg01<<<agg_grid, 256, 0, stream>>>((const float4*)XL, (const float4*)XR, (const float4*)RES,
        at0, b0, rowptr, csrc, Xh, Xl_);

    // --- Layer 1 ---
    k_gemm_mfma<128, false><<<dim3(gemm_gx, 3), 256, 0, stream>>>(nullptr, Xh, Xl_,
        th[3], tl[3], bl1, th[4], tl[4], br1, th[5], tl[5], XL, XR, RES);
    k_agg01<<<agg_grid, 256, 0, stream>>>((const float4*)XL, (const float4*)XR, (const float4*)RES,
        at1, b1, rowptr, csrc, Xh, Xl_);

    // --- Layer 2 (heads=1, C=64, no residual, no ELU) ---
    k_gemm_mfma<64, false><<<dim3(gemm_gx, 2), 256, 0, stream>>>(nullptr, Xh, Xl_,
        th[6], tl[6], bl2, th[7], tl[7], br2, nullptr, nullptr, XL, XR, nullptr);
    k_agg2<<<agg_grid, 256, 0, stream>>>((const float4*)XL, (const float4*)XR, at2, b2, rowptr, csrc, out);
}

// Round 11
// 417.584 us; speedup vs baseline: 1.1349x; 1.1045x over previous
//
#include <hip/hip_runtime.h>
#include <math.h>

// Problem constants (from reference)
#define NN 50000
#define EE 800000
#define NB ((NN + 255) / 256)   // scan blocks

typedef short v8s __attribute__((ext_vector_type(8)));
typedef float v4f __attribute__((ext_vector_type(4)));

__device__ __forceinline__ ushort f2bf(float f) {
    uint u = __float_as_uint(f);
    uint r = (u + 0x7fffu + ((u >> 16) & 1u)) >> 16;
    return (ushort)r;
}
__device__ __forceinline__ float bf2f(ushort h) {
    return __uint_as_float(((uint)h) << 16);
}
// leaky_relu(x,0.2) = 0.6x + 0.4|x|
__device__ __forceinline__ float lrelu(float x) {
    return fmaf(0.4f, fabsf(x), 0.6f * x);
}

// DPP partial reductions (no LDS pipe).
template <int CTRL>
__device__ __forceinline__ float dppadd(float x) {
    int y = __builtin_amdgcn_update_dpp(0, __float_as_int(x), CTRL, 0xf, 0xf, true);
    return x + __int_as_float(y);
}
__device__ __forceinline__ float sum8(float x) {   // all-lane sum within 8-groups
    x = dppadd<0xB1>(x);    // quad_perm xor1
    x = dppadd<0x4E>(x);    // quad_perm xor2
    x = dppadd<0x141>(x);   // row_half_mirror
    return x;
}
__device__ __forceinline__ float sum16(float x) {  // all-lane sum within 16-rows
    x = sum8(x);
    x = dppadd<0x140>(x);   // row_mirror
    return x;
}
__device__ __forceinline__ float expclamp(float t) {
    return __expf(fminf(fmaxf(t, -60.f), 80.f));
}

// ---------------------------------------------------------------------------
// CSR build: histogram -> 2-kernel parallel scan -> scatter
// ---------------------------------------------------------------------------
__global__ __launch_bounds__(256) void k_hist(const int* __restrict__ dst, int* __restrict__ deg) {
    int e = blockIdx.x * 256 + threadIdx.x;
    if (e < EE) atomicAdd(&deg[dst[e]], 1);
}

__global__ __launch_bounds__(256) void k_scan1(const int* __restrict__ deg, int* __restrict__ bsum) {
    __shared__ int sm[4];
    int t = threadIdx.x;
    int idx = blockIdx.x * 256 + t;
    int x = (idx < NN) ? deg[idx] : 0;
    #pragma unroll
    for (int o = 1; o < 64; o <<= 1) x += __shfl_xor(x, o);
    if ((t & 63) == 0) sm[t >> 6] = x;
    __syncthreads();
    if (t == 0) bsum[blockIdx.x] = sm[0] + sm[1] + sm[2] + sm[3];
}

// scan3 with fused block-offset: each block locally scans the NB-entry bsum
// (NB=196 <= 256) to get its own exclusive offset, then scans its 256 degs.
__global__ __launch_bounds__(256) void k_scan3(const int* __restrict__ deg,
                                               const int* __restrict__ bsum,
                                               int* __restrict__ rowptr,
                                               int* __restrict__ cursor) {
    __shared__ int sb[256];
    __shared__ int sm[256];
    int t = threadIdx.x;
    sb[t] = (t < NB) ? bsum[t] : 0;
    __syncthreads();
    for (int o = 1; o < 256; o <<= 1) {
        int a = (t >= o) ? sb[t - o] : 0;
        __syncthreads();
        sb[t] += a;
        __syncthreads();
    }
    const int boff = (blockIdx.x > 0) ? sb[blockIdx.x - 1] : 0;

    int idx = blockIdx.x * 256 + t;
    int v = (idx < NN) ? deg[idx] : 0;
    sm[t] = v;
    __syncthreads();
    for (int o = 1; o < 256; o <<= 1) {
        int a = (t >= o) ? sm[t - o] : 0;
        __syncthreads();
        sm[t] += a;
        __syncthreads();
    }
    int incl = sm[t] + boff;
    if (idx < NN) { rowptr[idx + 1] = incl; cursor[idx] = incl - v; }
    if (idx == 0) rowptr[0] = 0;
}

__global__ __launch_bounds__(256) void k_scatter(const int* __restrict__ src,
                                                 const int* __restrict__ dst,
                                                 int* __restrict__ cursor,
                                                 int* __restrict__ csrc) {
    int e = blockIdx.x * 256 + threadIdx.x;
    if (e < EE) {
        int d = dst[e];
        int pos = atomicAdd(&cursor[d], 1);
        csrc[pos] = src[e];
    }
}

// ---------------------------------------------------------------------------
// Weight conversion: W [128 x FOUT] fp32 -> bf16 hi/lo in MFMA-fragment order:
// element (col = t*16+m, k = c*32+quad*8+j) at (((t*4+c)*4+quad)*16+m)*8+j.
// ---------------------------------------------------------------------------
struct WPack {
    const float* W[8];
    ushort* Th[8];
    ushort* Tl[8];
    int fout[8];
};

__global__ __launch_bounds__(256) void k_conv_w(WPack p) {
    int wi = blockIdx.y;
    int fout = p.fout[wi];
    int total = 128 * fout;
    int i = blockIdx.x * 256 + threadIdx.x;
    if (i >= total) return;
    int k = i / fout;
    int n = i - k * fout;
    float f = p.W[wi][i];
    ushort h = f2bf(f);
    float lo = f - bf2f(h);
    int t = n >> 4, m = n & 15, c = k >> 5, quad = (k >> 3) & 3, j = k & 7;
    int flat = ((((t * 4 + c) * 4 + quad) * 16 + m) << 3) + j;
    p.Th[wi][flat] = h;
    p.Tl[wi][flat] = f2bf(lo);
}

// ---------------------------------------------------------------------------
// Split-bf16 MFMA GEMM: 64 rows per block (one 16-row strip per wave),
// blockIdx.y = weight matrix (w). w==0 (the XL output, consumed by the random
// gather in aggregation) is stored as bf16 — halves the compulsory per-XCD
// L2-fill traffic of the gather; w>0 (XR, RES, node-side coalesced single
// reads) stay fp32. B fragments read from fragment-packed global (L2-resident).
// CVT=true: A read from fp32 X, split hi/lo on the fly (layer 0).
// ---------------------------------------------------------------------------
template <int FOUT, bool CVT>
__global__ __launch_bounds__(256) void k_gemm_mfma(
    const float* __restrict__ Xf,
    const ushort* __restrict__ Xh, const ushort* __restrict__ Xl,
    const ushort* __restrict__ T0h, const ushort* __restrict__ T0l, const float* __restrict__ B0,
    const ushort* __restrict__ T1h, const ushort* __restrict__ T1l, const float* __restrict__ B1,
    const ushort* __restrict__ T2h, const ushort* __restrict__ T2l,
    ushort* __restrict__ O0b, float* __restrict__ O1, float* __restrict__ O2)
{
    const int lane = threadIdx.x & 63;
    const int wid  = threadIdx.x >> 6;
    const int m    = lane & 15;
    const int quad = lane >> 4;
    const int row0 = blockIdx.x * 64 + wid * 16;
    const int w    = blockIdx.y;

    const ushort* Th[3] = {T0h, T1h, T2h};
    const ushort* Tl[3] = {T0l, T1l, T2l};
    const float*  Bp[3] = {B0, B1, nullptr};
    const ushort* th = Th[w];
    const ushort* tl = Tl[w];
    const float* bias = Bp[w];
    float* Of = (w == 1) ? O1 : O2;

    v8s ah[4], al[4];
    {
        int arow = row0 + m;
        if (arow > NN - 1) arow = NN - 1;
        #pragma unroll
        for (int c = 0; c < 4; ++c) {
            size_t off = (size_t)arow * 128 + c * 32 + quad * 8;
            if constexpr (CVT) {
                float4 f0 = *(const float4*)(Xf + off);
                float4 f1 = *(const float4*)(Xf + off + 4);
                const float fe[8] = {f0.x, f0.y, f0.z, f0.w, f1.x, f1.y, f1.z, f1.w};
                #pragma unroll
                for (int e = 0; e < 8; ++e) {
                    ushort h = f2bf(fe[e]);
                    float lo = fe[e] - bf2f(h);
                    ah[c][e] = (short)h;
                    al[c][e] = (short)(__float_as_uint(lo) >> 16);  // truncate lo
                }
            } else {
                ah[c] = *(const v8s*)(Xh + off);
                al[c] = *(const v8s*)(Xl + off);
            }
        }
    }

    #pragma unroll
    for (int t = 0; t < FOUT / 16; ++t) {
        v4f acc = {0.f, 0.f, 0.f, 0.f};
        #pragma unroll
        for (int c = 0; c < 4; ++c) {
            int boff = t * 2048 + (c * 4 + quad) * 128 + m * 8;
            v8s bh = *(const v8s*)(th + boff);
            v8s bl = *(const v8s*)(tl + boff);
            acc = __builtin_amdgcn_mfma_f32_16x16x32_bf16(al[c], bh, acc, 0, 0, 0);
            acc = __builtin_amdgcn_mfma_f32_16x16x32_bf16(ah[c], bl, acc, 0, 0, 0);
            acc = __builtin_amdgcn_mfma_f32_16x16x32_bf16(ah[c], bh, acc, 0, 0, 0);
        }
        const int col = t * 16 + m;
        float badd = bias ? bias[col] : 0.f;
        if (w == 0) {
            #pragma unroll
            for (int j = 0; j < 4; ++j) {
                int r = row0 + quad * 4 + j;
                if (r < NN) O0b[(size_t)r * FOUT + col] = f2bf(acc[j] + badd);
            }
        } else {
            #pragma unroll
            for (int j = 0; j < 4; ++j) {
                int r = row0 + quad * 4 + j;
                if (r < NN) Of[(size_t)r * FOUT + col] = acc[j] + badd;
            }
        }
    }
}

// ---------------------------------------------------------------------------
// Aggregation layers 0/1: one wave per node, 4-edge main loop + tail.
// XL gathered as bf16 (ushort4, 8 B/lane) — halves the gather traffic.
// Lane l: half = l>>5 selects edge of the pair; j = l&31 owns channels
// 4j..4j+3. Head = j>>3 -> logit reduce = sum8 (3 DPP).
// Epilogue: +res +bias, ELU, emit bf16 hi/lo for the next GEMM.
// ---------------------------------------------------------------------------
__global__ __launch_bounds__(256) void k_agg01(const ushort* __restrict__ XLb,
                                               const float4* __restrict__ XR4,
                                               const float4* __restrict__ RES4,
                                               const float* __restrict__ att,
                                               const float* __restrict__ bias,
                                               const int* __restrict__ rowptr,
                                               const int* __restrict__ csrc,
                                               ushort* __restrict__ Hh,
                                               ushort* __restrict__ Hl) {
    const int lane = threadIdx.x & 63;
    const int wid = threadIdx.x >> 6;
    const int n = blockIdx.x * 4 + wid;
    if (n >= NN) return;
    const int beg = rowptr[n];
    const int end = rowptr[n + 1];
    const int half = lane >> 5;
    const uint j = lane & 31;

    const float4 xr = XR4[(uint)n * 32u + j];
    const float4 at = ((const float4*)att)[j];
    float4 s = {0.f, 0.f, 0.f, 0.f};
    float d = 0.f;

    int i = beg;
    for (; i + 4 <= end; i += 4) {
        uint sa = (uint)csrc[i + half];
        uint sb = (uint)csrc[i + 2 + half];
        ushort4 ua = *(const ushort4*)(XLb + sa * 128u + 4u * j);
        ushort4 ub = *(const ushort4*)(XLb + sb * 128u + 4u * j);
        {
            float4 va = {bf2f(ua.x), bf2f(ua.y), bf2f(ua.z), bf2f(ua.w)};
            float t0 = lrelu(va.x + xr.x) * at.x;
            t0 = fmaf(lrelu(va.y + xr.y), at.y, t0);
            t0 = fmaf(lrelu(va.z + xr.z), at.z, t0);
            t0 = fmaf(lrelu(va.w + xr.w), at.w, t0);
            float p = expclamp(sum8(t0));
            d += p;
            s.x = fmaf(p, va.x, s.x); s.y = fmaf(p, va.y, s.y);
            s.z = fmaf(p, va.z, s.z); s.w = fmaf(p, va.w, s.w);
        }
        {
            float4 vb = {bf2f(ub.x), bf2f(ub.y), bf2f(ub.z), bf2f(ub.w)};
            float t0 = lrelu(vb.x + xr.x) * at.x;
            t0 = fmaf(lrelu(vb.y + xr.y), at.y, t0);
            t0 = fmaf(lrelu(vb.z + xr.z), at.z, t0);
            t0 = fmaf(lrelu(vb.w + xr.w), at.w, t0);
            float p = expclamp(sum8(t0));
            d += p;
            s.x = fmaf(p, vb.x, s.x); s.y = fmaf(p, vb.y, s.y);
            s.z = fmaf(p, vb.z, s.z); s.w = fmaf(p, vb.w, s.w);
        }
    }
    for (; i < end; i += 2) {
        int ia = i + half;
        if (ia > end - 1) ia = end - 1;
        uint sa = (uint)csrc[ia];
        ushort4 ua = *(const ushort4*)(XLb + sa * 128u + 4u * j);
        float4 va = {bf2f(ua.x), bf2f(ua.y), bf2f(ua.z), bf2f(ua.w)};
        float t0 = lrelu(va.x + xr.x) * at.x;
        t0 = fmaf(lrelu(va.y + xr.y), at.y, t0);
        t0 = fmaf(lrelu(va.z + xr.z), at.z, t0);
        t0 = fmaf(lrelu(va.w + xr.w), at.w, t0);
        float p = expclamp(sum8(t0));
        if (half && (i + 1 >= end)) p = 0.f;
        d += p;
        s.x = fmaf(p, va.x, s.x); s.y = fmaf(p, va.y, s.y);
        s.z = fmaf(p, va.z, s.z); s.w = fmaf(p, va.w, s.w);
    }

    d   += __shfl_xor(d, 32);
    s.x += __shfl_xor(s.x, 32);
    s.y += __shfl_xor(s.y, 32);
    s.z += __shfl_xor(s.z, 32);
    s.w += __shfl_xor(s.w, 32);

    if (half == 0) {
        float inv = (d > 0.f) ? 1.f / d : 0.f;
        float4 rv = RES4[(uint)n * 32u + j];
        float4 bv = ((const float4*)bias)[j];
        float o0 = fmaf(s.x, inv, rv.x + bv.x);
        float o1 = fmaf(s.y, inv, rv.y + bv.y);
        float o2 = fmaf(s.z, inv, rv.z + bv.z);
        float o3 = fmaf(s.w, inv, rv.w + bv.w);
        o0 = o0 > 0.f ? o0 : __expf(o0) - 1.f;   // ELU
        o1 = o1 > 0.f ? o1 : __expf(o1) - 1.f;
        o2 = o2 > 0.f ? o2 : __expf(o2) - 1.f;
        o3 = o3 > 0.f ? o3 : __expf(o3) - 1.f;
        ushort4 h, l;
        h.x = f2bf(o0); l.x = f2bf(o0 - bf2f(h.x));
        h.y = f2bf(o1); l.y = f2bf(o1 - bf2f(h.y));
        h.z = f2bf(o2); l.z = f2bf(o2 - bf2f(h.z));
        h.w = f2bf(o3); l.w = f2bf(o3 - bf2f(h.w));
        *(ushort4*)(Hh + (uint)n * 128u + 4u * j) = h;
        *(ushort4*)(Hl + (uint)n * 128u + 4u * j) = l;
    }
}

// ---------------------------------------------------------------------------
// Aggregation layer 2: F=64, H=1, XL gathered as bf16. 8 edges per iteration
// (2 masked quad-passes). Quarter q = l>>4 selects edge; jj = l&15 owns
// channels 4jj..4jj+3. reduce16 = 4 DPP.
// ---------------------------------------------------------------------------
__global__ __launch_bounds__(256) void k_agg2(const ushort* __restrict__ XLb,
                                              const float4* __restrict__ XR4,
                                              const float* __restrict__ att,
                                              const float* __restrict__ bias,
                                              const int* __restrict__ rowptr,
                                              const int* __restrict__ csrc,
                                              float* __restrict__ OUT) {
    const int lane = threadIdx.x & 63;
    const int wid = threadIdx.x >> 6;
    const int n = blockIdx.x * 4 + wid;
    if (n >= NN) return;
    const int beg = rowptr[n];
    const int end = rowptr[n + 1];
    const int q = lane >> 4;
    const uint jj = lane & 15;

    const float4 xr = XR4[(uint)n * 16u + jj];
    const float4 at = ((const float4*)att)[jj];
    float4 s = {0.f, 0.f, 0.f, 0.f};
    float d = 0.f;
    const int e1 = end - 1;

    for (int i = beg; i < end; i += 8) {
        int i0 = i + q;
        int i1 = i + 4 + q;
        uint s0 = (uint)csrc[min(i0, e1)];
        uint s1 = (uint)csrc[min(i1, e1)];
        ushort4 u0 = *(const ushort4*)(XLb + s0 * 64u + 4u * jj);
        ushort4 u1 = *(const ushort4*)(XLb + s1 * 64u + 4u * jj);
        #pragma unroll
        for (int u = 0; u < 2; ++u) {
            ushort4 uv = (u == 0) ? u0 : u1;
            int ii = (u == 0) ? i0 : i1;
            float4 v = {bf2f(uv.x), bf2f(uv.y), bf2f(uv.z), bf2f(uv.w)};
            float t0 = lrelu(v.x + xr.x) * at.x;
            t0 = fmaf(lrelu(v.y + xr.y), at.y, t0);
            t0 = fmaf(lrelu(v.z + xr.z), at.z, t0);
            t0 = fmaf(lrelu(v.w + xr.w), at.w, t0);
            float p = expclamp(sum16(t0));
            if (ii >= end) p = 0.f;
            d += p;
            s.x = fmaf(p, v.x, s.x); s.y = fmaf(p, v.y, s.y);
            s.z = fmaf(p, v.z, s.z); s.w = fmaf(p, v.w, s.w);
        }
    }

    d   += __shfl_xor(d, 16);   d   += __shfl_xor(d, 32);
    s.x += __shfl_xor(s.x, 16); s.x += __shfl_xor(s.x, 32);
    s.y += __shfl_xor(s.y, 16); s.y += __shfl_xor(s.y, 32);
    s.z += __shfl_xor(s.z, 16); s.z += __shfl_xor(s.z, 32);
    s.w += __shfl_xor(s.w, 16); s.w += __shfl_xor(s.w, 32);

    if (lane < 16) {
        float inv = (d > 0.f) ? 1.f / d : 0.f;
        float4 bv = ((const float4*)bias)[jj];
        float4 o;
        o.x = fmaf(s.x, inv, bv.x);
        o.y = fmaf(s.y, inv, bv.y);
        o.z = fmaf(s.z, inv, bv.z);
        o.w = fmaf(s.w, inv, bv.w);
        *(float4*)(OUT + (uint)n * 64u + 4u * jj) = o;
    }
}

// ---------------------------------------------------------------------------
extern "C" void kernel_launch(void* const* d_in, const int* in_sizes, int n_in,
                              void* d_out, int out_size, void* d_ws, size_t ws_size,
                              hipStream_t stream) {
    const float* x    = (const float*)d_in[0];
    const int*   ei   = (const int*)d_in[1];
    const int*   esrc = ei;
    const int*   edst = ei + EE;

    const float* Wl0 = (const float*)d_in[2];
    const float* bl0 = (const float*)d_in[3];
    const float* Wr0 = (const float*)d_in[4];
    const float* br0 = (const float*)d_in[5];
    const float* at0 = (const float*)d_in[6];
    const float* b0  = (const float*)d_in[7];
    const float* rs0 = (const float*)d_in[8];
    const float* Wl1 = (const float*)d_in[9];
    const float* bl1 = (const float*)d_in[10];
    const float* Wr1 = (const float*)d_in[11];
    const float* br1 = (const float*)d_in[12];
    const float* at1 = (const float*)d_in[13];
    const float* b1  = (const float*)d_in[14];
    const float* rs1 = (const float*)d_in[15];
    const float* Wl2 = (const float*)d_in[16];
    const float* bl2 = (const float*)d_in[17];
    const float* Wr2 = (const float*)d_in[18];
    const float* br2 = (const float*)d_in[19];
    const float* at2 = (const float*)d_in[20];
    const float* b2  = (const float*)d_in[21];

    float* out = (float*)d_out;

    // --- workspace layout ---
    ushort* XLb = (ushort*)d_ws;               // [NN*128] bf16 (gather payload)
    float* XR  = (float*)(XLb + (size_t)NN * 128);    // [NN*128] fp32
    float* RES = XR + (size_t)NN * 128;               // [NN*128] fp32
    ushort* Xh = (ushort*)(RES + (size_t)NN * 128);   // [NN*128] bf16-hi (H)
    ushort* Xl_ = Xh + (size_t)NN * 128;              // [NN*128] bf16-lo (H)
    ushort* Wth = Xl_ + (size_t)NN * 128;
    const int wsz[8] = {16384, 16384, 16384, 16384, 16384, 16384, 8192, 8192};
    ushort* th[8]; ushort* tl[8];
    {
        ushort* p = Wth;
        for (int i = 0; i < 8; ++i) { th[i] = p; p += wsz[i]; }
        for (int i = 0; i < 8; ++i) { tl[i] = p; p += wsz[i]; }
    }
    int* deg    = (int*)(Wth + 2 * (6 * 16384 + 2 * 8192));
    int* rowptr = deg + NN;                    // NN+1
    int* cursor = rowptr + (NN + 1);
    int* csrc   = cursor + NN;                 // EE
    int* bsum   = csrc + EE;                   // NB

    // --- CSR build (graph identical across layers) ---
    hipMemsetAsync(deg, 0, NN * sizeof(int), stream);
    k_hist<<<(EE + 255) / 256, 256, 0, stream>>>(edst, deg);
    k_scan1<<<NB, 256, 0, stream>>>(deg, bsum);
    k_scan3<<<NB, 256, 0, stream>>>(deg, bsum, rowptr, cursor);
    k_scatter<<<(EE + 255) / 256, 256, 0, stream>>>(esrc, edst, cursor, csrc);

    // --- weight conversion ---
    WPack wp;
    const float* Ws[8] = {Wl0, Wr0, rs0, Wl1, Wr1, rs1, Wl2, Wr2};
    const int fouts[8] = {128, 128, 128, 128, 128, 128, 64, 64};
    for (int i = 0; i < 8; ++i) { wp.W[i] = Ws[i]; wp.Th[i] = th[i]; wp.Tl[i] = tl[i]; wp.fout[i] = fouts[i]; }
    k_conv_w<<<dim3(64, 8), 256, 0, stream>>>(wp);

    const int gemm_gx = (NN + 63) / 64;        // 782 row-tiles
    const int agg_grid = (NN + 3) / 4;

    // --- Layer 0 (A from fp32 x, split on the fly; grid.y = weight matrix) ---
    k_gemm_mfma<128, true><<<dim3(gemm_gx, 3), 256, 0, stream>>>(x, nullptr, nullptr,
        th[0], tl[0], bl0, th[1], tl[1], br0, th[2], tl[2], XLb, XR, RES);
    k_agg01<<<agg_grid, 256, 0, stream>>>(XLb, (const float4*)XR, (const float4*)RES,
        at0, b0, rowptr, csrc, Xh, Xl_);

    // --- Layer 1 ---
    k_gemm_mfma<128, false><<<dim3(gemm_gx, 3), 256, 0, stream>>>(nullptr, Xh, Xl_,
        th[3], tl[3], bl1, th[4], tl[4], br1, th[5], tl[5], XLb, XR, RES);
    k_agg01<<<agg_grid, 256, 0, stream>>>(XLb, (const float4*)XR, (const float4*)RES,
        at1, b1, rowptr, csrc, Xh, Xl_);

    // --- Layer 2 (heads=1, C=64, no residual, no ELU) ---
    k_gemm_mfma<64, false><<<dim3(gemm_gx, 2), 256, 0, stream>>>(nullptr, Xh, Xl_,
        th[6], tl[6], bl2, th[7], tl[7], br2, nullptr, nullptr, XLb, XR, nullptr);
    k_agg2<<<agg_grid, 256, 0, stream>>>(XLb, (const float4*)XR, at2, b2, rowptr, csrc, out);
}

// Round 12
// 366.504 us; speedup vs baseline: 1.2931x; 1.1394x over previous
//
#include <hip/hip_runtime.h>
#include <math.h>

// Problem constants (from reference)
#define NN 50000
#define EE 800000
#define NBK 196    // node buckets (256 nodes each): ceil(50000/256)
#define EPB 4096   // edges per pass-A block: ceil(800000/4096) = 196 blocks

typedef short v8s __attribute__((ext_vector_type(8)));
typedef float v4f __attribute__((ext_vector_type(4)));

__device__ __forceinline__ ushort f2bf(float f) {
    uint u = __float_as_uint(f);
    uint r = (u + 0x7fffu + ((u >> 16) & 1u)) >> 16;
    return (ushort)r;
}
__device__ __forceinline__ float bf2f(ushort h) {
    return __uint_as_float(((uint)h) << 16);
}
// leaky_relu(x,0.2) = 0.6x + 0.4|x|
__device__ __forceinline__ float lrelu(float x) {
    return fmaf(0.4f, fabsf(x), 0.6f * x);
}

// DPP partial reductions (no LDS pipe).
template <int CTRL>
__device__ __forceinline__ float dppadd(float x) {
    int y = __builtin_amdgcn_update_dpp(0, __float_as_int(x), CTRL, 0xf, 0xf, true);
    return x + __int_as_float(y);
}
__device__ __forceinline__ float sum8(float x) {   // all-lane sum within 8-groups
    x = dppadd<0xB1>(x);    // quad_perm xor1
    x = dppadd<0x4E>(x);    // quad_perm xor2
    x = dppadd<0x141>(x);   // row_half_mirror
    return x;
}
__device__ __forceinline__ float sum16(float x) {  // all-lane sum within 16-rows
    x = sum8(x);
    x = dppadd<0x140>(x);   // row_mirror
    return x;
}
__device__ __forceinline__ float expclamp(float t) {
    return __expf(fminf(fmaxf(t, -60.f), 80.f));
}

// ---------------------------------------------------------------------------
// Bucketed CSR build — no per-node global atomics, no random global writes.
// Buckets = 256-node ranges. ebuf holds edges bucket-ordered, packed
// (dstlow<<16)|src (both < 2^16). All fine-grained scatter happens in LDS or
// within a bucket's 16 KB csrc window (L2-resident).
// ---------------------------------------------------------------------------
__global__ __launch_bounds__(256) void k_bktcnt(const int* __restrict__ edst,
                                                int* __restrict__ bcnt) {
    __shared__ int h[NBK];
    int t = threadIdx.x;
    if (t < NBK) h[t] = 0;
    __syncthreads();
    int eb = blockIdx.x * EPB;
    #pragma unroll
    for (int k = 0; k < EPB / 256; ++k) {
        int e = eb + k * 256 + t;
        if (e < EE) atomicAdd(&h[edst[e] >> 8], 1);
    }
    __syncthreads();
    if (t < NBK && h[t]) atomicAdd(&bcnt[t], h[t]);
}

__global__ __launch_bounds__(256) void k_bscan(const int* __restrict__ bcnt,
                                               int* __restrict__ bbase,
                                               int* __restrict__ bcur) {
    __shared__ int sm[256];
    int t = threadIdx.x;
    int v = (t < NBK) ? bcnt[t] : 0;
    sm[t] = v;
    __syncthreads();
    for (int o = 1; o < 256; o <<= 1) {
        int a = (t >= o) ? sm[t - o] : 0;
        __syncthreads();
        sm[t] += a;
        __syncthreads();
    }
    if (t < NBK) { int ex = sm[t] - v; bbase[t] = ex; bcur[t] = ex; }
}

__global__ __launch_bounds__(256) void k_bktplace(const int* __restrict__ esrc,
                                                  const int* __restrict__ edst,
                                                  int* __restrict__ bcur,
                                                  uint* __restrict__ ebuf) {
    __shared__ int h[NBK];
    __shared__ int base[NBK];
    int t = threadIdx.x;
    if (t < NBK) h[t] = 0;
    __syncthreads();
    int eb = blockIdx.x * EPB;
    int pk[EPB / 256];   // (bucket<<16)|local_rank per edge
    #pragma unroll
    for (int k = 0; k < EPB / 256; ++k) {
        int e = eb + k * 256 + t;
        pk[k] = -1;
        if (e < EE) {
            int b = edst[e] >> 8;
            int r = atomicAdd(&h[b], 1);
            pk[k] = (b << 16) | r;
        }
    }
    __syncthreads();
    if (t < NBK && h[t]) base[t] = atomicAdd(&bcur[t], h[t]);
    __syncthreads();
    #pragma unroll
    for (int k = 0; k < EPB / 256; ++k) {
        int e = eb + k * 256 + t;
        if (e < EE) {
            int b = pk[k] >> 16;
            int r = pk[k] & 0xFFFF;
            uint dl = (uint)(edst[e] & 255);
            ebuf[base[b] + r] = (dl << 16) | (uint)esrc[e];
        }
    }
}

// one block per bucket: per-node degree + scan + cursor all in LDS.
__global__ __launch_bounds__(256) void k_bktfin(const uint* __restrict__ ebuf,
                                                const int* __restrict__ bbase,
                                                const int* __restrict__ bcnt,
                                                int* __restrict__ rowptr,
                                                int* __restrict__ csrc) {
    __shared__ int deg[256];
    __shared__ int sm[256];
    __shared__ int cur[256];
    const int b = blockIdx.x;
    const int t = threadIdx.x;
    const int eb = bbase[b];
    const int ec = bcnt[b];
    deg[t] = 0;
    __syncthreads();
    for (int k = t; k < ec; k += 256)
        atomicAdd(&deg[ebuf[eb + k] >> 16], 1);
    __syncthreads();
    int v = deg[t];
    sm[t] = v;
    __syncthreads();
    for (int o = 1; o < 256; o <<= 1) {
        int a = (t >= o) ? sm[t - o] : 0;
        __syncthreads();
        sm[t] += a;
        __syncthreads();
    }
    int node = b * 256 + t;
    if (node < NN) rowptr[node + 1] = eb + sm[t];
    if (node == 0) rowptr[0] = 0;
    cur[t] = sm[t] - v;   // exclusive
    __syncthreads();
    for (int k = t; k < ec; k += 256) {
        uint u = ebuf[eb + k];
        int nl = (int)(u >> 16);
        int r = atomicAdd(&cur[nl], 1);
        csrc[eb + r] = (int)(u & 0xFFFFu);
    }
}

// ---------------------------------------------------------------------------
// Weight conversion: W [128 x FOUT] fp32 -> bf16 hi/lo in MFMA-fragment order:
// element (col = t*16+m, k = c*32+quad*8+j) at (((t*4+c)*4+quad)*16+m)*8+j.
// ---------------------------------------------------------------------------
struct WPack {
    const float* W[8];
    ushort* Th[8];
    ushort* Tl[8];
    int fout[8];
};

__global__ __launch_bounds__(256) void k_conv_w(WPack p) {
    int wi = blockIdx.y;
    int fout = p.fout[wi];
    int total = 128 * fout;
    int i = blockIdx.x * 256 + threadIdx.x;
    if (i >= total) return;
    int k = i / fout;
    int n = i - k * fout;
    float f = p.W[wi][i];
    ushort h = f2bf(f);
    float lo = f - bf2f(h);
    int t = n >> 4, m = n & 15, c = k >> 5, quad = (k >> 3) & 3, j = k & 7;
    int flat = ((((t * 4 + c) * 4 + quad) * 16 + m) << 3) + j;
    p.Th[wi][flat] = h;
    p.Tl[wi][flat] = f2bf(lo);
}

// ---------------------------------------------------------------------------
// Split-bf16 MFMA GEMM: 64 rows per block (one 16-row strip per wave),
// blockIdx.y = weight matrix (w). w==0 (XL, consumed by the random gather)
// stored bf16; w>0 (XR, RES — coalesced node-side reads) fp32.
// CVT=true: A read from fp32 X, split hi/lo on the fly (layer 0).
// ---------------------------------------------------------------------------
template <int FOUT, bool CVT>
__global__ __launch_bounds__(256) void k_gemm_mfma(
    const float* __restrict__ Xf,
    const ushort* __restrict__ Xh, const ushort* __restrict__ Xl,
    const ushort* __restrict__ T0h, const ushort* __restrict__ T0l, const float* __restrict__ B0,
    const ushort* __restrict__ T1h, const ushort* __restrict__ T1l, const float* __restrict__ B1,
    const ushort* __restrict__ T2h, const ushort* __restrict__ T2l,
    ushort* __restrict__ O0b, float* __restrict__ O1, float* __restrict__ O2)
{
    const int lane = threadIdx.x & 63;
    const int wid  = threadIdx.x >> 6;
    const int m    = lane & 15;
    const int quad = lane >> 4;
    const int row0 = blockIdx.x * 64 + wid * 16;
    const int w    = blockIdx.y;

    const ushort* Th[3] = {T0h, T1h, T2h};
    const ushort* Tl[3] = {T0l, T1l, T2l};
    const float*  Bp[3] = {B0, B1, nullptr};
    const ushort* th = Th[w];
    const ushort* tl = Tl[w];
    const float* bias = Bp[w];
    float* Of = (w == 1) ? O1 : O2;

    v8s ah[4], al[4];
    {
        int arow = row0 + m;
        if (arow > NN - 1) arow = NN - 1;
        #pragma unroll
        for (int c = 0; c < 4; ++c) {
            size_t off = (size_t)arow * 128 + c * 32 + quad * 8;
            if constexpr (CVT) {
                float4 f0 = *(const float4*)(Xf + off);
                float4 f1 = *(const float4*)(Xf + off + 4);
                const float fe[8] = {f0.x, f0.y, f0.z, f0.w, f1.x, f1.y, f1.z, f1.w};
                #pragma unroll
                for (int e = 0; e < 8; ++e) {
                    ushort h = f2bf(fe[e]);
                    float lo = fe[e] - bf2f(h);
                    ah[c][e] = (short)h;
                    al[c][e] = (short)(__float_as_uint(lo) >> 16);  // truncate lo
                }
            } else {
                ah[c] = *(const v8s*)(Xh + off);
                al[c] = *(const v8s*)(Xl + off);
            }
        }
    }

    #pragma unroll
    for (int t = 0; t < FOUT / 16; ++t) {
        v4f acc = {0.f, 0.f, 0.f, 0.f};
        #pragma unroll
        for (int c = 0; c < 4; ++c) {
            int boff = t * 2048 + (c * 4 + quad) * 128 + m * 8;
            v8s bh = *(const v8s*)(th + boff);
            v8s bl = *(const v8s*)(tl + boff);
            acc = __builtin_amdgcn_mfma_f32_16x16x32_bf16(al[c], bh, acc, 0, 0, 0);
            acc = __builtin_amdgcn_mfma_f32_16x16x32_bf16(ah[c], bl, acc, 0, 0, 0);
            acc = __builtin_amdgcn_mfma_f32_16x16x32_bf16(ah[c], bh, acc, 0, 0, 0);
        }
        const int col = t * 16 + m;
        float badd = bias ? bias[col] : 0.f;
        if (w == 0) {
            #pragma unroll
            for (int j = 0; j < 4; ++j) {
                int r = row0 + quad * 4 + j;
                if (r < NN) O0b[(size_t)r * FOUT + col] = f2bf(acc[j] + badd);
            }
        } else {
            #pragma unroll
            for (int j = 0; j < 4; ++j) {
                int r = row0 + quad * 4 + j;
                if (r < NN) Of[(size_t)r * FOUT + col] = acc[j] + badd;
            }
        }
    }
}

// ---------------------------------------------------------------------------
// Aggregation layers 0/1: one wave per node, 4-edge main loop + tail.
// XL gathered as bf16 (ushort4, 8 B/lane). Lane l: half = l>>5 selects edge
// of the pair; j = l&31 owns channels 4j..4j+3. Head = j>>3 -> sum8 (3 DPP).
// Epilogue: +res +bias, ELU, emit bf16 hi/lo for the next GEMM.
// ---------------------------------------------------------------------------
__global__ __launch_bounds__(256) void k_agg01(const ushort* __restrict__ XLb,
                                               const float4* __restrict__ XR4,
                                               const float4* __restrict__ RES4,
                                               const float* __restrict__ att,
                                               const float* __restrict__ bias,
                                               const int* __restrict__ rowptr,
                                               const int* __restrict__ csrc,
                                               ushort* __restrict__ Hh,
                                               ushort* __restrict__ Hl) {
    const int lane = threadIdx.x & 63;
    const int wid = threadIdx.x >> 6;
    const int n = blockIdx.x * 4 + wid;
    if (n >= NN) return;
    const int beg = rowptr[n];
    const int end = rowptr[n + 1];
    const int half = lane >> 5;
    const uint j = lane & 31;

    const float4 xr = XR4[(uint)n * 32u + j];
    const float4 at = ((const float4*)att)[j];
    float4 s = {0.f, 0.f, 0.f, 0.f};
    float d = 0.f;

    int i = beg;
    for (; i + 4 <= end; i += 4) {
        uint sa = (uint)csrc[i + half];
        uint sb = (uint)csrc[i + 2 + half];
        ushort4 ua = *(const ushort4*)(XLb + sa * 128u + 4u * j);
        ushort4 ub = *(const ushort4*)(XLb + sb * 128u + 4u * j);
        {
            float4 va = {bf2f(ua.x), bf2f(ua.y), bf2f(ua.z), bf2f(ua.w)};
            float t0 = lrelu(va.x + xr.x) * at.x;
            t0 = fmaf(lrelu(va.y + xr.y), at.y, t0);
            t0 = fmaf(lrelu(va.z + xr.z), at.z, t0);
            t0 = fmaf(lrelu(va.w + xr.w), at.w, t0);
            float p = expclamp(sum8(t0));
            d += p;
            s.x = fmaf(p, va.x, s.x); s.y = fmaf(p, va.y, s.y);
            s.z = fmaf(p, va.z, s.z); s.w = fmaf(p, va.w, s.w);
        }
        {
            float4 vb = {bf2f(ub.x), bf2f(ub.y), bf2f(ub.z), bf2f(ub.w)};
            float t0 = lrelu(vb.x + xr.x) * at.x;
            t0 = fmaf(lrelu(vb.y + xr.y), at.y, t0);
            t0 = fmaf(lrelu(vb.z + xr.z), at.z, t0);
            t0 = fmaf(lrelu(vb.w + xr.w), at.w, t0);
            float p = expclamp(sum8(t0));
            d += p;
            s.x = fmaf(p, vb.x, s.x); s.y = fmaf(p, vb.y, s.y);
            s.z = fmaf(p, vb.z, s.z); s.w = fmaf(p, vb.w, s.w);
        }
    }
    for (; i < end; i += 2) {
        int ia = i + half;
        if (ia > end - 1) ia = end - 1;
        uint sa = (uint)csrc[ia];
        ushort4 ua = *(const ushort4*)(XLb + sa * 128u + 4u * j);
        float4 va = {bf2f(ua.x), bf2f(ua.y), bf2f(ua.z), bf2f(ua.w)};
        float t0 = lrelu(va.x + xr.x) * at.x;
        t0 = fmaf(lrelu(va.y + xr.y), at.y, t0);
        t0 = fmaf(lrelu(va.z + xr.z), at.z, t0);
        t0 = fmaf(lrelu(va.w + xr.w), at.w, t0);
        float p = expclamp(sum8(t0));
        if (half && (i + 1 >= end)) p = 0.f;
        d += p;
        s.x = fmaf(p, va.x, s.x); s.y = fmaf(p, va.y, s.y);
        s.z = fmaf(p, va.z, s.z); s.w = fmaf(p, va.w, s.w);
    }

    d   += __shfl_xor(d, 32);
    s.x += __shfl_xor(s.x, 32);
    s.y += __shfl_xor(s.y, 32);
    s.z += __shfl_xor(s.z, 32);
    s.w += __shfl_xor(s.w, 32);

    if (half == 0) {
        float inv = (d > 0.f) ? 1.f / d : 0.f;
        float4 rv = RES4[(uint)n * 32u + j];
        float4 bv = ((const float4*)bias)[j];
        float o0 = fmaf(s.x, inv, rv.x + bv.x);
        float o1 = fmaf(s.y, inv, rv.y + bv.y);
        float o2 = fmaf(s.z, inv, rv.z + bv.z);
        float o3 = fmaf(s.w, inv, rv.w + bv.w);
        o0 = o0 > 0.f ? o0 : __expf(o0) - 1.f;   // ELU
        o1 = o1 > 0.f ? o1 : __expf(o1) - 1.f;
        o2 = o2 > 0.f ? o2 : __expf(o2) - 1.f;
        o3 = o3 > 0.f ? o3 : __expf(o3) - 1.f;
        ushort4 h, l;
        h.x = f2bf(o0); l.x = f2bf(o0 - bf2f(h.x));
        h.y = f2bf(o1); l.y = f2bf(o1 - bf2f(h.y));
        h.z = f2bf(o2); l.z = f2bf(o2 - bf2f(h.z));
        h.w = f2bf(o3); l.w = f2bf(o3 - bf2f(h.w));
        *(ushort4*)(Hh + (uint)n * 128u + 4u * j) = h;
        *(ushort4*)(Hl + (uint)n * 128u + 4u * j) = l;
    }
}

// ---------------------------------------------------------------------------
// Aggregation layer 2: F=64, H=1, XL gathered as bf16. 8 edges per iteration
// (2 masked quad-passes). Quarter q = l>>4 selects edge; jj = l&15 owns
// channels 4jj..4jj+3. reduce16 = 4 DPP.
// ---------------------------------------------------------------------------
__global__ __launch_bounds__(256) void k_agg2(const ushort* __restrict__ XLb,
                                              const float4* __restrict__ XR4,
                                              const float* __restrict__ att,
                                              const float* __restrict__ bias,
                                              const int* __restrict__ rowptr,
                                              const int* __restrict__ csrc,
                                              float* __restrict__ OUT) {
    const int lane = threadIdx.x & 63;
    const int wid = threadIdx.x >> 6;
    const int n = blockIdx.x * 4 + wid;
    if (n >= NN) return;
    const int beg = rowptr[n];
    const int end = rowptr[n + 1];
    const int q = lane >> 4;
    const uint jj = lane & 15;

    const float4 xr = XR4[(uint)n * 16u + jj];
    const float4 at = ((const float4*)att)[jj];
    float4 s = {0.f, 0.f, 0.f, 0.f};
    float d = 0.f;
    const int e1 = end - 1;

    for (int i = beg; i < end; i += 8) {
        int i0 = i + q;
        int i1 = i + 4 + q;
        uint s0 = (uint)csrc[min(i0, e1)];
        uint s1 = (uint)csrc[min(i1, e1)];
        ushort4 u0 = *(const ushort4*)(XLb + s0 * 64u + 4u * jj);
        ushort4 u1 = *(const ushort4*)(XLb + s1 * 64u + 4u * jj);
        #pragma unroll
        for (int u = 0; u < 2; ++u) {
            ushort4 uv = (u == 0) ? u0 : u1;
            int ii = (u == 0) ? i0 : i1;
            float4 v = {bf2f(uv.x), bf2f(uv.y), bf2f(uv.z), bf2f(uv.w)};
            float t0 = lrelu(v.x + xr.x) * at.x;
            t0 = fmaf(lrelu(v.y + xr.y), at.y, t0);
            t0 = fmaf(lrelu(v.z + xr.z), at.z, t0);
            t0 = fmaf(lrelu(v.w + xr.w), at.w, t0);
            float p = expclamp(sum16(t0));
            if (ii >= end) p = 0.f;
            d += p;
            s.x = fmaf(p, v.x, s.x); s.y = fmaf(p, v.y, s.y);
            s.z = fmaf(p, v.z, s.z); s.w = fmaf(p, v.w, s.w);
        }
    }

    d   += __shfl_xor(d, 16);   d   += __shfl_xor(d, 32);
    s.x += __shfl_xor(s.x, 16); s.x += __shfl_xor(s.x, 32);
    s.y += __shfl_xor(s.y, 16); s.y += __shfl_xor(s.y, 32);
    s.z += __shfl_xor(s.z, 16); s.z += __shfl_xor(s.z, 32);
    s.w += __shfl_xor(s.w, 16); s.w += __shfl_xor(s.w, 32);

    if (lane < 16) {
        float inv = (d > 0.f) ? 1.f / d : 0.f;
        float4 bv = ((const float4*)bias)[jj];
        float4 o;
        o.x = fmaf(s.x, inv, bv.x);
        o.y = fmaf(s.y, inv, bv.y);
        o.z = fmaf(s.z, inv, bv.z);
        o.w = fmaf(s.w, inv, bv.w);
        *(float4*)(OUT + (uint)n * 64u + 4u * jj) = o;
    }
}

// ---------------------------------------------------------------------------
extern "C" void kernel_launch(void* const* d_in, const int* in_sizes, int n_in,
                              void* d_out, int out_size, void* d_ws, size_t ws_size,
                              hipStream_t stream) {
    const float* x    = (const float*)d_in[0];
    const int*   ei   = (const int*)d_in[1];
    const int*   esrc = ei;
    const int*   edst = ei + EE;

    const float* Wl0 = (const float*)d_in[2];
    const float* bl0 = (const float*)d_in[3];
    const float* Wr0 = (const float*)d_in[4];
    const float* br0 = (const float*)d_in[5];
    const float* at0 = (const float*)d_in[6];
    const float* b0  = (const float*)d_in[7];
    const float* rs0 = (const float*)d_in[8];
    const float* Wl1 = (const float*)d_in[9];
    const float* bl1 = (const float*)d_in[10];
    const float* Wr1 = (const float*)d_in[11];
    const float* br1 = (const float*)d_in[12];
    const float* at1 = (const float*)d_in[13];
    const float* b1  = (const float*)d_in[14];
    const float* rs1 = (const float*)d_in[15];
    const float* Wl2 = (const float*)d_in[16];
    const float* bl2 = (const float*)d_in[17];
    const float* Wr2 = (const float*)d_in[18];
    const float* br2 = (const float*)d_in[19];
    const float* at2 = (const float*)d_in[20];
    const float* b2  = (const float*)d_in[21];

    float* out = (float*)d_out;

    // --- workspace layout ---
    ushort* XLb = (ushort*)d_ws;               // [NN*128] bf16 (gather payload)
    float* XR  = (float*)(XLb + (size_t)NN * 128);    // [NN*128] fp32
    float* RES = XR + (size_t)NN * 128;               // [NN*128] fp32
    ushort* Xh = (ushort*)(RES + (size_t)NN * 128);   // [NN*128] bf16-hi (H)
    ushort* Xl_ = Xh + (size_t)NN * 128;              // [NN*128] bf16-lo (H)
    ushort* Wth = Xl_ + (size_t)NN * 128;
    const int wsz[8] = {16384, 16384, 16384, 16384, 16384, 16384, 8192, 8192};
    ushort* th[8]; ushort* tl[8];
    {
        ushort* p = Wth;
        for (int i = 0; i < 8; ++i) { th[i] = p; p += wsz[i]; }
        for (int i = 0; i < 8; ++i) { tl[i] = p; p += wsz[i]; }
    }
    int* bcnt   = (int*)(Wth + 2 * (6 * 16384 + 2 * 8192));  // 256 (memset)
    int* bbase  = bcnt + 256;                  // 256
    int* bcur   = bbase + 256;                 // 256
    int* rowptr = bcur + 256;                  // NN+1
    int* csrc   = rowptr + (NN + 1);           // EE
    uint* ebuf  = (uint*)(csrc + EE);          // EE

    // --- bucketed CSR build (graph identical across layers) ---
    hipMemsetAsync(bcnt, 0, 256 * sizeof(int), stream);
    const int ebk = (EE + EPB - 1) / EPB;      // 196
    k_bktcnt<<<ebk, 256, 0, stream>>>(edst, bcnt);
    k_bscan<<<1, 256, 0, stream>>>(bcnt, bbase, bcur);
    k_bktplace<<<ebk, 256, 0, stream>>>(esrc, edst, bcur, ebuf);
    k_bktfin<<<NBK, 256, 0, stream>>>(ebuf, bbase, bcnt, rowptr, csrc);

    // --- weight conversion ---
    WPack wp;
    const float* Ws[8] = {Wl0, Wr0, rs0, Wl1, Wr1, rs1, Wl2, Wr2};
    const int fouts[8] = {128, 128, 128, 128, 128, 128, 64, 64};
    for (int i = 0; i < 8; ++i) { wp.W[i] = Ws[i]; wp.Th[i] = th[i]; wp.Tl[i] = tl[i]; wp.fout[i] = fouts[i]; }
    k_conv_w<<<dim3(64, 8), 256, 0, stream>>>(wp);

    const int gemm_gx = (NN + 63) / 64;        // 782 row-tiles
    const int agg_grid = (NN + 3) / 4;

    // --- Layer 0 (A from fp32 x, split on the fly; grid.y = weight matrix) ---
    k_gemm_mfma<128, true><<<dim3(gemm_gx, 3), 256, 0, stream>>>(x, nullptr, nullptr,
        th[0], tl[0], bl0, th[1], tl[1], br0, th[2], tl[2], XLb, XR, RES);
    k_agg01<<<agg_grid, 256, 0, stream>>>(XLb, (const float4*)XR, (const float4*)RES,
        at0, b0, rowptr, csrc, Xh, Xl_);

    // --- Layer 1 ---
    k_gemm_mfma<128, false><<<dim3(gemm_gx, 3), 256, 0, stream>>>(nullptr, Xh, Xl_,
        th[3], tl[3], bl1, th[4], tl[4], br1, th[5], tl[5], XLb, XR, RES);
    k_agg01<<<agg_grid, 256, 0, stream>>>(XLb, (const float4*)XR, (const float4*)RES,
        at1, b1, rowptr, csrc, Xh, Xl_);

    // --- Layer 2 (heads=1, C=64, no residual, no ELU) ---
    k_gemm_mfma<64, false><<<dim3(gemm_gx, 2), 256, 0, stream>>>(nullptr, Xh, Xl_,
        th[6], tl[6], bl2, th[7], tl[7], br2, nullptr, nullptr, XLb, XR, nullptr);
    k_agg2<<<agg_grid, 256, 0, stream>>>(XLb, (const float4*)XR, at2, b2, rowptr, csrc, out);
}